// Round 1
// baseline (413.519 us; speedup 1.0000x reference)
//
#include <hip/hip_runtime.h>

#define NNODES 50000
#define NEDGES 800000

using short8 = __attribute__((ext_vector_type(8))) short;   // 8 bf16 (4 VGPRs)
using f32x4  = __attribute__((ext_vector_type(4))) float;   // MFMA accumulator

// fp32 -> bf16 round-to-nearest-even
__device__ __forceinline__ short f2b(float v) {
    unsigned u = __builtin_bit_cast(unsigned, v);
    u = (u + 0x7FFFu + ((u >> 16) & 1u)) >> 16;
    return (short)u;
}

// order-preserving float->uint encoding (for atomicMax). enc is strictly
// increasing in float order; every finite float encodes > 0, so 0 is a safe
// "empty" sentinel (maps to PyG's zero-fill of empty segments).
__device__ __forceinline__ unsigned encf(float v) {
    unsigned u = __builtin_bit_cast(unsigned, v);
    return (u & 0x80000000u) ? ~u : (u | 0x80000000u);
}

// Fused: gather feats -> Linear(160,256)+ReLU -> Linear(256,64) -> out writes
// + atomicMax scatter into encoded agg.
// Per block: 256 edges, 8 waves, each wave owns 32 edges (2 M-frags of 16).
// W1/W2 staged in LDS as bf16 packed in MFMA B-fragment order.
__global__ __launch_bounds__(512)
void edgeconv_mlp(const float* __restrict__ x, const int* __restrict__ ei,
                  const float* __restrict__ ea, const float* __restrict__ W1,
                  const float* __restrict__ b1, const float* __restrict__ W2,
                  const float* __restrict__ b2, float* __restrict__ outbuf,
                  unsigned* __restrict__ aggbuf)
{
    __shared__ short w1p[40960];     // 80 KB: W1 [160][256] packed
    __shared__ short w2p[16384];     // 32 KB: W2 [256][64]  packed
    __shared__ short hbuf[8][2048];  // 32 KB: per-wave h tile 32x64 bf16, swizzled

    const int tid = threadIdx.x;

    // ---- stage weights (bf16, B-fragment packed order) ----
    // W1 elem (k,n) -> w1p[(((n>>4)*20 + (k>>3))*16 + (n&15))*8 + (k&7)]
    for (int i = tid; i < 40960; i += 512) {
        int k = i >> 8, n = i & 255;
        int dst = (((((n >> 4) * 20 + (k >> 3)) << 4) | (n & 15)) << 3) | (k & 7);
        w1p[dst] = f2b(W1[i]);
    }
    // W2 elem (k,n) -> w2p[(((n>>4)*32 + (k>>3))*16 + (n&15))*8 + (k&7)]
    for (int i = tid; i < 16384; i += 512) {
        int k = i >> 6, n = i & 63;
        int dst = (((((n >> 4) * 32 + (k >> 3)) << 4) | (n & 15)) << 3) | (k & 7);
        w2p[dst] = f2b(W2[i]);
    }
    __syncthreads();

    const int wave = tid >> 6, lane = tid & 63;
    const int l16 = lane & 15, lg = lane >> 4;       // A-frag: row=l16, k-chunk=lg
    const int ebase = blockIdx.x * 256 + wave * 32;
    short* hw = hbuf[wave];

    // ---- gather A1 fragments straight from global (fp32 -> bf16) ----
    // lane holds feats[e = ebase+mf*16+l16][k0 .. k0+7], k0 = kk*32 + lg*8
    short8 A1[2][5];
    #pragma unroll
    for (int mf = 0; mf < 2; ++mf) {
        int e = ebase + mf * 16 + l16;
        int r = ei[e], c = ei[NEDGES + e];
        #pragma unroll
        for (int kk = 0; kk < 5; ++kk) {
            int k0 = kk * 32 + lg * 8;
            const float* src;
            if (kk < 2)      src = x + r * 64 + k0;          // x[row], k 0..63
            else if (kk < 4) src = x + c * 64 + (k0 - 64);   // x[col], k 64..127
            else             src = ea + e * 32 + (k0 - 128); // edge_attr, k 128..159
            float4 va = reinterpret_cast<const float4*>(src)[0];
            float4 vb = reinterpret_cast<const float4*>(src)[1];
            short8 f;
            f[0]=f2b(va.x); f[1]=f2b(va.y); f[2]=f2b(va.z); f[3]=f2b(va.w);
            f[4]=f2b(vb.x); f[5]=f2b(vb.y); f[6]=f2b(vb.z); f[7]=f2b(vb.w);
            A1[mf][kk] = f;
        }
    }

    f32x4 acc2[2][4] = {};   // GEMM2 accumulators: 2 mf x 4 n-tiles (64 out cols)

    // 4 phases of 64 H-columns each; GEMM2 K accumulated across phases
    for (int ph = 0; ph < 4; ++ph) {
        // ---- GEMM1: h[:, ph*64 .. ph*64+63] ----
        f32x4 acc1[2][4] = {};
        #pragma unroll
        for (int kk = 0; kk < 5; ++kk) {
            int kc8 = kk * 4 + lg;
            #pragma unroll
            for (int ntl = 0; ntl < 4; ++ntl) {
                int nt = ph * 4 + ntl;
                const short8 bf = *reinterpret_cast<const short8*>(
                    &w1p[(((nt * 20 + kc8) << 4) | l16) << 3]);
                acc1[0][ntl] = __builtin_amdgcn_mfma_f32_16x16x32_bf16(A1[0][kk], bf, acc1[0][ntl], 0, 0, 0);
                acc1[1][ntl] = __builtin_amdgcn_mfma_f32_16x16x32_bf16(A1[1][kk], bf, acc1[1][ntl], 0, 0, 0);
            }
        }
        // bias + ReLU + bf16, write to swizzled per-wave LDS tile
        // D-frag: row = lg*4+q (within mf), col = l16 (within nt)
        #pragma unroll
        for (int mf = 0; mf < 2; ++mf) {
            #pragma unroll
            for (int ntl = 0; ntl < 4; ++ntl) {
                int col = ntl * 16 + l16;
                float bias = b1[ph * 64 + col];
                #pragma unroll
                for (int q = 0; q < 4; ++q) {
                    int row = mf * 16 + lg * 4 + q;
                    float v = fmaxf(acc1[mf][ntl][q] + bias, 0.0f);
                    int off = row * 128 + ((col * 2) ^ ((row & 7) << 4));
                    *reinterpret_cast<short*>(reinterpret_cast<char*>(hw) + off) = f2b(v);
                }
            }
        }
        __syncthreads();   // h writes visible (also orders same-wave ds ops)

        // ---- GEMM2 partial: K-chunk [ph*64, ph*64+64) ----
        #pragma unroll
        for (int kk2 = 0; kk2 < 2; ++kk2) {
            short8 a2[2];
            #pragma unroll
            for (int mf = 0; mf < 2; ++mf) {
                int row = mf * 16 + l16;
                int klocal = kk2 * 32 + lg * 8;
                int off = row * 128 + ((klocal * 2) ^ ((row & 7) << 4));
                a2[mf] = *reinterpret_cast<const short8*>(reinterpret_cast<char*>(hw) + off);
            }
            int kc8g = ph * 8 + kk2 * 4 + lg;
            #pragma unroll
            for (int nt2 = 0; nt2 < 4; ++nt2) {
                const short8 bf2 = *reinterpret_cast<const short8*>(
                    &w2p[(((nt2 * 32 + kc8g) << 4) | l16) << 3]);
                acc2[0][nt2] = __builtin_amdgcn_mfma_f32_16x16x32_bf16(a2[0], bf2, acc2[0][nt2], 0, 0, 0);
                acc2[1][nt2] = __builtin_amdgcn_mfma_f32_16x16x32_bf16(a2[1], bf2, acc2[1][nt2], 0, 0, 0);
            }
        }
        __syncthreads();   // reads done before next phase overwrites hbuf
    }

    // ---- epilogue: +b2, store out, atomicMax-scatter encoded agg ----
    #pragma unroll
    for (int mf = 0; mf < 2; ++mf) {
        #pragma unroll
        for (int nt2 = 0; nt2 < 4; ++nt2) {
            int col = nt2 * 16 + l16;
            float bias = b2[col];
            #pragma unroll
            for (int q = 0; q < 4; ++q) {
                int e2 = ebase + mf * 16 + lg * 4 + q;
                float v = acc2[mf][nt2][q] + bias;
                outbuf[e2 * 64 + col] = v;
                int rn = ei[e2];                       // source node (row)
                atomicMax(&aggbuf[rn * 64 + col], encf(v));
            }
        }
    }
}

// decode encoded agg in place: sentinel 0 -> 0.0f (empty segment), else inverse map
__global__ void decode_agg(unsigned* __restrict__ agg)
{
    int i = blockIdx.x * 256 + threadIdx.x;
    if (i < NNODES * 64) {
        unsigned u = agg[i];
        float f;
        if (u == 0u)                 f = 0.0f;
        else if (u & 0x80000000u)    f = __builtin_bit_cast(float, u ^ 0x80000000u);
        else                         f = __builtin_bit_cast(float, ~u);
        reinterpret_cast<float*>(agg)[i] = f;
    }
}

extern "C" void kernel_launch(void* const* d_in, const int* in_sizes, int n_in,
                              void* d_out, int out_size, void* d_ws, size_t ws_size,
                              hipStream_t stream)
{
    const float* x  = (const float*)d_in[0];
    const int*   ei = (const int*)d_in[1];
    const float* ea = (const float*)d_in[2];
    const float* W1 = (const float*)d_in[3];
    const float* b1 = (const float*)d_in[4];
    const float* W2 = (const float*)d_in[5];
    const float* b2 = (const float*)d_in[6];
    float* outp = (float*)d_out;

    // agg region (N*64 u32) -> sentinel 0 ("empty")
    hipMemsetAsync(d_out, 0, (size_t)NNODES * 64 * sizeof(float), stream);
    edgeconv_mlp<<<NEDGES / 256, 512, 0, stream>>>(
        x, ei, ea, W1, b1, W2, b2,
        outp + (size_t)NNODES * 64,     // out section
        (unsigned*)d_out);              // agg section (encoded)
    decode_agg<<<(NNODES * 64 + 255) / 256, 256, 0, stream>>>((unsigned*)d_out);
}